// Round 10
// baseline (18.913 us; speedup 1.0000x reference)
//
#include <hip/hip_runtime.h>
#include <hip/hip_bf16.h>

// Problem constants (fixed: H=W=128, C=64, K=3, HID=256, OUT_C=3, scale=2)
#define H_IN 128
#define W_IN 128
#define C_IN 64
#define HID 256
#define OUT_C 3
#define OUT_W 256
#define NW 1728   // 3*3*64*3 weights per parity
#define PPW 4     // pixels per wave in the einsum phase (R10: was 8)

__device__ __forceinline__ float rdlane(float v, int l) {
    return __int_as_float(__builtin_amdgcn_readlane(__float_as_int(v), l));
}

// ---------------------------------------------------------------------------
// K1: ENTIRE MLP, one kernel, 108 blocks x 256 (R9-validated, unchanged).
// k3 loads issued first so their cold-HBM latency hides under the k2 matmul.
// ---------------------------------------------------------------------------
__global__ __launch_bounds__(256) void mlp_all_kernel(
    const float* __restrict__ k1, const float* __restrict__ b1,
    const float* __restrict__ k2, const float* __restrict__ b2,
    const float* __restrict__ k3, const float* __restrict__ b3,
    float* __restrict__ wout)
{
    __shared__ float sPart[4][4][256];   // [wave][par][n]  16 KB
    __shared__ float sH2[4][256];        // [par][n]         4 KB
    __shared__ float sR[4][4][16];       // [wave][par][c]   1 KB
    const int tid  = threadIdx.x;
    const int lane = tid & 63;
    const int w    = tid >> 6;

    // ---- phase 2 address setup + EARLY k3 loads (independent of h2)
    const int c    = tid & 15;
    const int sg   = lane >> 4;           // 0..3
    const int mbase = (w * 4 + sg) * 16;  // 0..240, step 16
    const int n    = blockIdx.x * 16 + c; // k3 column 0..1727
    float kv[16];
#pragma unroll
    for (int j = 0; j < 16; ++j)
        kv[j] = k3[(size_t)(mbase + j) * NW + n];

    // ---- phase 1a: h1 for this wave's m-slice (m = w*64+lane), 4 parities
    const int m = w * 64 + lane;
    const float k10 = k1[m], k11 = k1[HID + m], k12 = k1[2 * HID + m];
    const float b1m = b1[m];
    float h1r[4];
    h1r[0] = fmaxf(0.5f * k12 + b1m, 0.0f);
    h1r[1] = fmaxf(0.5f * k11 + 0.5f * k12 + b1m, 0.0f);
    h1r[2] = fmaxf(0.5f * k10 + 0.5f * k12 + b1m, 0.0f);
    h1r[3] = fmaxf(0.5f * k10 + 0.5f * k11 + 0.5f * k12 + b1m, 0.0f);

    // ---- phase 1b: partial h2: wave w covers m in [64w,64w+64),
    //      cols 4*lane..4*lane+3 (float4), all 4 parities.
    float4 acc[4];
#pragma unroll
    for (int p = 0; p < 4; ++p) acc[p] = make_float4(0.f, 0.f, 0.f, 0.f);
    const float* k2p = k2 + (w * 64) * HID + 4 * lane;
#pragma unroll
    for (int i = 0; i < 64; ++i) {
        const float4 kvv = *reinterpret_cast<const float4*>(k2p + i * HID);
#pragma unroll
        for (int p = 0; p < 4; ++p) {
            const float hm = rdlane(h1r[p], i);
            acc[p].x = fmaf(hm, kvv.x, acc[p].x);
            acc[p].y = fmaf(hm, kvv.y, acc[p].y);
            acc[p].z = fmaf(hm, kvv.z, acc[p].z);
            acc[p].w = fmaf(hm, kvv.w, acc[p].w);
        }
    }
#pragma unroll
    for (int p = 0; p < 4; ++p)
        *reinterpret_cast<float4*>(&sPart[w][p][4 * lane]) = acc[p];
    __syncthreads();

    // ---- phase 1c: reduce 4 waves -> h2 (relu) in LDS
    const float b2v = b2[tid];
#pragma unroll
    for (int p = 0; p < 4; ++p) {
        const float s = b2v + sPart[0][p][tid] + sPart[1][p][tid]
                      + sPart[2][p][tid] + sPart[3][p][tid];
        sH2[p][tid] = fmaxf(s, 0.0f);
    }
    __syncthreads();

    // ---- phase 2: this block's 16 k3 columns (kv already in registers)
    float pr[4];
#pragma unroll
    for (int p = 0; p < 4; ++p) {
        float s = 0.0f;
#pragma unroll
        for (int q = 0; q < 4; ++q) {
            const float4 h4 = *reinterpret_cast<const float4*>(
                &sH2[p][mbase + 4 * q]);
            s = fmaf(h4.x, kv[4 * q + 0], s);
            s = fmaf(h4.y, kv[4 * q + 1], s);
            s = fmaf(h4.z, kv[4 * q + 2], s);
            s = fmaf(h4.w, kv[4 * q + 3], s);
        }
        pr[p] = s;
    }
#pragma unroll
    for (int p = 0; p < 4; ++p) {
        pr[p] += __shfl_xor(pr[p], 16);
        pr[p] += __shfl_xor(pr[p], 32);
    }
    if (lane < 16) {
#pragma unroll
        for (int p = 0; p < 4; ++p) sR[w][p][lane] = pr[p];
    }
    __syncthreads();

    if (tid < 64) {
        const int fp = tid >> 4, fc = tid & 15;
        const int fn = blockIdx.x * 16 + fc;
        const float total = b3[fn] + sR[0][fp][fc] + sR[1][fp][fc]
                          + sR[2][fp][fc] + sR[3][fp][fc];
        // fn = ((pp*3+q)*64 + ch)*3 + o  ->  [par][o][pq][ch]
        const int o = fn % 3;
        const int rest = fn / 3;
        const int cch = rest & 63;
        const int pq = rest >> 6;
        wout[fp * NW + (o * 9 + pq) * 64 + cch] = total;
    }
}

// ---------------------------------------------------------------------------
// K2: the einsum, LDS-staged, R10: 1024 blocks x 256 (16-col groups, PPW=4)
// for 4 blocks/CU latency overlap. bid -> (iy = bid>>3, cg = bid&7).
// Stage rows iy-1..iy+1, cols [cg*16-1, cg*16+17) x 64 ch = 13.8 KB, one
// coalesced round. FMA/reduction core = validated R8/R9 code.
// ---------------------------------------------------------------------------
__global__ __launch_bounds__(256) void upscale_kernel(
    const float* __restrict__ feat, const float* __restrict__ wts,
    float* __restrict__ out)
{
    __shared__ float sF[3][18][64];      // 13824 B
    const int tid  = threadIdx.x;
    const int lane = tid & 63;
    const int w    = tid >> 6;
    const int iy   = blockIdx.x >> 3;    // input row 0..127
    const int cg   = blockIdx.x & 7;     // column group (16 cols)
    const int par  = lane >> 4;          // 0..3
    const int c4   = lane & 15;          // channel quad
    const int pi = par >> 1, pj = par & 1;
    const float4 fz = make_float4(0.f, 0.f, 0.f, 0.f);

    // ---- weight preamble loads issued first (independent of staging)
    float4 wreg[3][9];
#pragma unroll
    for (int o = 0; o < 3; ++o)
#pragma unroll
        for (int pq = 0; pq < 9; ++pq)
            wreg[o][pq] = *reinterpret_cast<const float4*>(
                wts + ((par * 3 + o) * 9 + pq) * 64 + c4 * 4);

    // ---- stage the 3x18x64 feature tile (zero-padded at borders)
    const int cbase = cg * 16 - 1;
#pragma unroll
    for (int idx = tid, it = 0; it < 4; ++it, idx += 256) {
        if (idx < 864) {                       // 3*18*16 float4 elements
            const int c4i = idx & 15;
            const int t   = idx >> 4;
            const int col = t % 18;
            const int r   = t / 18;
            const int grow = iy - 1 + r;
            const int gcol = cbase + col;
            float4 v = fz;
            if ((unsigned)grow < (unsigned)H_IN && (unsigned)gcol < (unsigned)W_IN)
                v = *reinterpret_cast<const float4*>(
                    feat + (grow * W_IN + gcol) * C_IN + c4i * 4);
            *reinterpret_cast<float4*>(&sF[r][col][c4i * 4]) = v;
        }
    }
    __syncthreads();

    // ---- compute: wave w covers pixels ix = cg*16 + w*4 + g, g = 0..3.
    // LDS window col for (g,q) is w*4 + g + q. Ring slots as validated.
    float4 fc0[3], fc1[3], fc2[3];
    auto ldl = [&](int col, float4& a, float4& b, float4& c) {
        a = *reinterpret_cast<const float4*>(&sF[0][col][c4 * 4]);
        b = *reinterpret_cast<const float4*>(&sF[1][col][c4 * 4]);
        c = *reinterpret_cast<const float4*>(&sF[2][col][c4 * 4]);
    };
    ldl(w * 4 + 0, fc0[0], fc1[0], fc2[0]);
    ldl(w * 4 + 1, fc0[1], fc1[1], fc2[1]);

#pragma unroll
    for (int g = 0; g < PPW; ++g) {
        const int sNew = (g + 2) % 3;
        ldl(w * 4 + g + 2, fc0[sNew], fc1[sNew], fc2[sNew]);

        float acc0 = 0.f, acc1 = 0.f, acc2 = 0.f;
#pragma unroll
        for (int q = 0; q < 3; ++q) {
            const int s = (g + q) % 3;
            const float4 f0 = fc0[s], f1 = fc1[s], f2 = fc2[s];
            const int pq0 = q, pq1 = 3 + q, pq2 = 6 + q;
            acc0 = fmaf(f0.x, wreg[0][pq0].x, acc0);
            acc0 = fmaf(f0.y, wreg[0][pq0].y, acc0);
            acc0 = fmaf(f0.z, wreg[0][pq0].z, acc0);
            acc0 = fmaf(f0.w, wreg[0][pq0].w, acc0);
            acc1 = fmaf(f0.x, wreg[1][pq0].x, acc1);
            acc1 = fmaf(f0.y, wreg[1][pq0].y, acc1);
            acc1 = fmaf(f0.z, wreg[1][pq0].z, acc1);
            acc1 = fmaf(f0.w, wreg[1][pq0].w, acc1);
            acc2 = fmaf(f0.x, wreg[2][pq0].x, acc2);
            acc2 = fmaf(f0.y, wreg[2][pq0].y, acc2);
            acc2 = fmaf(f0.z, wreg[2][pq0].z, acc2);
            acc2 = fmaf(f0.w, wreg[2][pq0].w, acc2);

            acc0 = fmaf(f1.x, wreg[0][pq1].x, acc0);
            acc0 = fmaf(f1.y, wreg[0][pq1].y, acc0);
            acc0 = fmaf(f1.z, wreg[0][pq1].z, acc0);
            acc0 = fmaf(f1.w, wreg[0][pq1].w, acc0);
            acc1 = fmaf(f1.x, wreg[1][pq1].x, acc1);
            acc1 = fmaf(f1.y, wreg[1][pq1].y, acc1);
            acc1 = fmaf(f1.z, wreg[1][pq1].z, acc1);
            acc1 = fmaf(f1.w, wreg[1][pq1].w, acc1);
            acc2 = fmaf(f1.x, wreg[2][pq1].x, acc2);
            acc2 = fmaf(f1.y, wreg[2][pq1].y, acc2);
            acc2 = fmaf(f1.z, wreg[2][pq1].z, acc2);
            acc2 = fmaf(f1.w, wreg[2][pq1].w, acc2);

            acc0 = fmaf(f2.x, wreg[0][pq2].x, acc0);
            acc0 = fmaf(f2.y, wreg[0][pq2].y, acc0);
            acc0 = fmaf(f2.z, wreg[0][pq2].z, acc0);
            acc0 = fmaf(f2.w, wreg[0][pq2].w, acc0);
            acc1 = fmaf(f2.x, wreg[1][pq2].x, acc1);
            acc1 = fmaf(f2.y, wreg[1][pq2].y, acc1);
            acc1 = fmaf(f2.z, wreg[1][pq2].z, acc1);
            acc1 = fmaf(f2.w, wreg[1][pq2].w, acc1);
            acc2 = fmaf(f2.x, wreg[2][pq2].x, acc2);
            acc2 = fmaf(f2.y, wreg[2][pq2].y, acc2);
            acc2 = fmaf(f2.z, wreg[2][pq2].z, acc2);
            acc2 = fmaf(f2.w, wreg[2][pq2].w, acc2);
        }

        // 8-shuffle reduction over 16 lanes for 3 values
        acc0 += __shfl_xor(acc0, 1); acc0 += __shfl_xor(acc0, 2);
        acc1 += __shfl_xor(acc1, 1); acc1 += __shfl_xor(acc1, 2);
        acc2 += __shfl_xor(acc2, 1); acc2 += __shfl_xor(acc2, 2);
        const int j = c4 & 3;
        float v = (j == 0) ? acc0 : ((j == 1) ? acc1 : acc2);
        v += __shfl_xor(v, 4);
        v += __shfl_xor(v, 8);
        if (c4 < 3) {
            const int oy = 2 * iy + pi;
            const int ox = 2 * (cg * 16 + w * 4 + g) + pj;
            out[(oy * OUT_W + ox) * OUT_C + c4] = v;
        }
    }
}

// ---------------------------------------------------------------------------
extern "C" void kernel_launch(void* const* d_in, const int* in_sizes, int n_in,
                              void* d_out, int out_size, void* d_ws, size_t ws_size,
                              hipStream_t stream)
{
    const float* feat = (const float*)d_in[0];
    const float* k1   = (const float*)d_in[1];
    const float* b1   = (const float*)d_in[2];
    const float* k2   = (const float*)d_in[3];
    const float* b2   = (const float*)d_in[4];
    const float* k3   = (const float*)d_in[5];
    const float* b3   = (const float*)d_in[6];
    float* out = (float*)d_out;
    float* wts = (float*)d_ws;   // 4*NW floats, [par][o][pq][c]

    mlp_all_kernel<<<108,  256, 0, stream>>>(k1, b1, k2, b2, k3, b3, wts);
    upscale_kernel<<<1024, 256, 0, stream>>>(feat, wts, out);
}

// Round 11
// 17.583 us; speedup vs baseline: 1.0756x; 1.0756x over previous
//
#include <hip/hip_runtime.h>
#include <hip/hip_bf16.h>

// Problem constants (fixed: H=W=128, C=64, K=3, HID=256, OUT_C=3, scale=2)
#define H_IN 128
#define W_IN 128
#define C_IN 64
#define HID 256
#define OUT_C 3
#define OUT_W 256
#define NW 1728   // 3*3*64*3 weights per parity
#define PPW 8     // pixels per wave in the einsum phase (R9 optimum)

__device__ __forceinline__ float rdlane(float v, int l) {
    return __int_as_float(__builtin_amdgcn_readlane(__float_as_int(v), l));
}

// ---------------------------------------------------------------------------
// K1: ENTIRE MLP, one kernel, 108 blocks x 256 (R9-validated, unchanged).
// k3 loads issued first so their cold-HBM latency hides under the k2 matmul.
// ---------------------------------------------------------------------------
__global__ __launch_bounds__(256) void mlp_all_kernel(
    const float* __restrict__ k1, const float* __restrict__ b1,
    const float* __restrict__ k2, const float* __restrict__ b2,
    const float* __restrict__ k3, const float* __restrict__ b3,
    float* __restrict__ wout)
{
    __shared__ float sPart[4][4][256];   // [wave][par][n]  16 KB
    __shared__ float sH2[4][256];        // [par][n]         4 KB
    __shared__ float sR[4][4][16];       // [wave][par][c]   1 KB
    const int tid  = threadIdx.x;
    const int lane = tid & 63;
    const int w    = tid >> 6;

    // ---- phase 2 address setup + EARLY k3 loads (independent of h2)
    const int c    = tid & 15;
    const int sg   = lane >> 4;           // 0..3
    const int mbase = (w * 4 + sg) * 16;  // 0..240, step 16
    const int n    = blockIdx.x * 16 + c; // k3 column 0..1727
    float kv[16];
#pragma unroll
    for (int j = 0; j < 16; ++j)
        kv[j] = k3[(size_t)(mbase + j) * NW + n];

    // ---- phase 1a: h1 for this wave's m-slice (m = w*64+lane), 4 parities
    const int m = w * 64 + lane;
    const float k10 = k1[m], k11 = k1[HID + m], k12 = k1[2 * HID + m];
    const float b1m = b1[m];
    float h1r[4];
    h1r[0] = fmaxf(0.5f * k12 + b1m, 0.0f);
    h1r[1] = fmaxf(0.5f * k11 + 0.5f * k12 + b1m, 0.0f);
    h1r[2] = fmaxf(0.5f * k10 + 0.5f * k12 + b1m, 0.0f);
    h1r[3] = fmaxf(0.5f * k10 + 0.5f * k11 + 0.5f * k12 + b1m, 0.0f);

    // ---- phase 1b: partial h2: wave w covers m in [64w,64w+64),
    //      cols 4*lane..4*lane+3 (float4), all 4 parities.
    float4 acc[4];
#pragma unroll
    for (int p = 0; p < 4; ++p) acc[p] = make_float4(0.f, 0.f, 0.f, 0.f);
    const float* k2p = k2 + (w * 64) * HID + 4 * lane;
#pragma unroll
    for (int i = 0; i < 64; ++i) {
        const float4 kvv = *reinterpret_cast<const float4*>(k2p + i * HID);
#pragma unroll
        for (int p = 0; p < 4; ++p) {
            const float hm = rdlane(h1r[p], i);
            acc[p].x = fmaf(hm, kvv.x, acc[p].x);
            acc[p].y = fmaf(hm, kvv.y, acc[p].y);
            acc[p].z = fmaf(hm, kvv.z, acc[p].z);
            acc[p].w = fmaf(hm, kvv.w, acc[p].w);
        }
    }
#pragma unroll
    for (int p = 0; p < 4; ++p)
        *reinterpret_cast<float4*>(&sPart[w][p][4 * lane]) = acc[p];
    __syncthreads();

    // ---- phase 1c: reduce 4 waves -> h2 (relu) in LDS
    const float b2v = b2[tid];
#pragma unroll
    for (int p = 0; p < 4; ++p) {
        const float s = b2v + sPart[0][p][tid] + sPart[1][p][tid]
                      + sPart[2][p][tid] + sPart[3][p][tid];
        sH2[p][tid] = fmaxf(s, 0.0f);
    }
    __syncthreads();

    // ---- phase 2: this block's 16 k3 columns (kv already in registers)
    float pr[4];
#pragma unroll
    for (int p = 0; p < 4; ++p) {
        float s = 0.0f;
#pragma unroll
        for (int q = 0; q < 4; ++q) {
            const float4 h4 = *reinterpret_cast<const float4*>(
                &sH2[p][mbase + 4 * q]);
            s = fmaf(h4.x, kv[4 * q + 0], s);
            s = fmaf(h4.y, kv[4 * q + 1], s);
            s = fmaf(h4.z, kv[4 * q + 2], s);
            s = fmaf(h4.w, kv[4 * q + 3], s);
        }
        pr[p] = s;
    }
#pragma unroll
    for (int p = 0; p < 4; ++p) {
        pr[p] += __shfl_xor(pr[p], 16);
        pr[p] += __shfl_xor(pr[p], 32);
    }
    if (lane < 16) {
#pragma unroll
        for (int p = 0; p < 4; ++p) sR[w][p][lane] = pr[p];
    }
    __syncthreads();

    if (tid < 64) {
        const int fp = tid >> 4, fc = tid & 15;
        const int fn = blockIdx.x * 16 + fc;
        const float total = b3[fn] + sR[0][fp][fc] + sR[1][fp][fc]
                          + sR[2][fp][fc] + sR[3][fp][fc];
        // fn = ((pp*3+q)*64 + ch)*3 + o  ->  [par][o][pq][ch]
        const int o = fn % 3;
        const int rest = fn / 3;
        const int cch = rest & 63;
        const int pq = rest >> 6;
        wout[fp * NW + (o * 9 + pq) * 64 + cch] = total;
    }
}

// ---------------------------------------------------------------------------
// K2: the einsum with block-level LDS staging (R9 optimum: 512 blocks x 256,
// 32-col groups, PPW=8). bid -> (iy = bid>>2, cg = bid&3). Block stages rows
// iy-1..iy+1, cols [cg*32-1, cg*32+33) x 64 ch (26 KB) in ONE coalesced
// latency round, then computes from LDS. FMA/reduction core validated.
// ---------------------------------------------------------------------------
__global__ __launch_bounds__(256) void upscale_kernel(
    const float* __restrict__ feat, const float* __restrict__ wts,
    float* __restrict__ out)
{
    __shared__ float sF[3][34][64];      // 26112 B
    const int tid  = threadIdx.x;
    const int lane = tid & 63;
    const int w    = tid >> 6;
    const int iy   = blockIdx.x >> 2;    // input row 0..127
    const int cg   = blockIdx.x & 3;     // column group (32 cols)
    const int par  = lane >> 4;          // 0..3
    const int c4   = lane & 15;          // channel quad
    const int pi = par >> 1, pj = par & 1;
    const float4 fz = make_float4(0.f, 0.f, 0.f, 0.f);

    // ---- weight preamble loads issued first (independent of staging)
    float4 wreg[3][9];
#pragma unroll
    for (int o = 0; o < 3; ++o)
#pragma unroll
        for (int pq = 0; pq < 9; ++pq)
            wreg[o][pq] = *reinterpret_cast<const float4*>(
                wts + ((par * 3 + o) * 9 + pq) * 64 + c4 * 4);

    // ---- stage the 3x34x64 feature tile (zero-padded at borders)
    const int cbase = cg * 32 - 1;
#pragma unroll
    for (int idx = tid, it = 0; it < 7; ++it, idx += 256) {
        if (idx < 1632) {                      // 3*34*16 float4 elements
            const int c4i = idx & 15;
            const int t   = idx >> 4;
            const int col = t % 34;
            const int r   = t / 34;
            const int grow = iy - 1 + r;
            const int gcol = cbase + col;
            float4 v = fz;
            if ((unsigned)grow < (unsigned)H_IN && (unsigned)gcol < (unsigned)W_IN)
                v = *reinterpret_cast<const float4*>(
                    feat + (grow * W_IN + gcol) * C_IN + c4i * 4);
            *reinterpret_cast<float4*>(&sF[r][col][c4i * 4]) = v;
        }
    }
    __syncthreads();

    // ---- compute: wave w covers pixels ix = cg*32 + w*8 + g, g = 0..7.
    float4 fc0[3], fc1[3], fc2[3];
    auto ldl = [&](int col, float4& a, float4& b, float4& c) {
        a = *reinterpret_cast<const float4*>(&sF[0][col][c4 * 4]);
        b = *reinterpret_cast<const float4*>(&sF[1][col][c4 * 4]);
        c = *reinterpret_cast<const float4*>(&sF[2][col][c4 * 4]);
    };
    ldl(w * 8 + 0, fc0[0], fc1[0], fc2[0]);
    ldl(w * 8 + 1, fc0[1], fc1[1], fc2[1]);

#pragma unroll
    for (int g = 0; g < PPW; ++g) {
        const int sNew = (g + 2) % 3;
        ldl(w * 8 + g + 2, fc0[sNew], fc1[sNew], fc2[sNew]);

        float acc0 = 0.f, acc1 = 0.f, acc2 = 0.f;
#pragma unroll
        for (int q = 0; q < 3; ++q) {
            const int s = (g + q) % 3;
            const float4 f0 = fc0[s], f1 = fc1[s], f2 = fc2[s];
            const int pq0 = q, pq1 = 3 + q, pq2 = 6 + q;
            acc0 = fmaf(f0.x, wreg[0][pq0].x, acc0);
            acc0 = fmaf(f0.y, wreg[0][pq0].y, acc0);
            acc0 = fmaf(f0.z, wreg[0][pq0].z, acc0);
            acc0 = fmaf(f0.w, wreg[0][pq0].w, acc0);
            acc1 = fmaf(f0.x, wreg[1][pq0].x, acc1);
            acc1 = fmaf(f0.y, wreg[1][pq0].y, acc1);
            acc1 = fmaf(f0.z, wreg[1][pq0].z, acc1);
            acc1 = fmaf(f0.w, wreg[1][pq0].w, acc1);
            acc2 = fmaf(f0.x, wreg[2][pq0].x, acc2);
            acc2 = fmaf(f0.y, wreg[2][pq0].y, acc2);
            acc2 = fmaf(f0.z, wreg[2][pq0].z, acc2);
            acc2 = fmaf(f0.w, wreg[2][pq0].w, acc2);

            acc0 = fmaf(f1.x, wreg[0][pq1].x, acc0);
            acc0 = fmaf(f1.y, wreg[0][pq1].y, acc0);
            acc0 = fmaf(f1.z, wreg[0][pq1].z, acc0);
            acc0 = fmaf(f1.w, wreg[0][pq1].w, acc0);
            acc1 = fmaf(f1.x, wreg[1][pq1].x, acc1);
            acc1 = fmaf(f1.y, wreg[1][pq1].y, acc1);
            acc1 = fmaf(f1.z, wreg[1][pq1].z, acc1);
            acc1 = fmaf(f1.w, wreg[1][pq1].w, acc1);
            acc2 = fmaf(f1.x, wreg[2][pq1].x, acc2);
            acc2 = fmaf(f1.y, wreg[2][pq1].y, acc2);
            acc2 = fmaf(f1.z, wreg[2][pq1].z, acc2);
            acc2 = fmaf(f1.w, wreg[2][pq1].w, acc2);

            acc0 = fmaf(f2.x, wreg[0][pq2].x, acc0);
            acc0 = fmaf(f2.y, wreg[0][pq2].y, acc0);
            acc0 = fmaf(f2.z, wreg[0][pq2].z, acc0);
            acc0 = fmaf(f2.w, wreg[0][pq2].w, acc0);
            acc1 = fmaf(f2.x, wreg[1][pq2].x, acc1);
            acc1 = fmaf(f2.y, wreg[1][pq2].y, acc1);
            acc1 = fmaf(f2.z, wreg[1][pq2].z, acc1);
            acc1 = fmaf(f2.w, wreg[1][pq2].w, acc1);
            acc2 = fmaf(f2.x, wreg[2][pq2].x, acc2);
            acc2 = fmaf(f2.y, wreg[2][pq2].y, acc2);
            acc2 = fmaf(f2.z, wreg[2][pq2].z, acc2);
            acc2 = fmaf(f2.w, wreg[2][pq2].w, acc2);
        }

        // 8-shuffle reduction over 16 lanes for 3 values
        acc0 += __shfl_xor(acc0, 1); acc0 += __shfl_xor(acc0, 2);
        acc1 += __shfl_xor(acc1, 1); acc1 += __shfl_xor(acc1, 2);
        acc2 += __shfl_xor(acc2, 1); acc2 += __shfl_xor(acc2, 2);
        const int j = c4 & 3;
        float v = (j == 0) ? acc0 : ((j == 1) ? acc1 : acc2);
        v += __shfl_xor(v, 4);
        v += __shfl_xor(v, 8);
        if (c4 < 3) {
            const int oy = 2 * iy + pi;
            const int ox = 2 * (cg * 32 + w * 8 + g) + pj;
            out[(oy * OUT_W + ox) * OUT_C + c4] = v;
        }
    }
}

// ---------------------------------------------------------------------------
extern "C" void kernel_launch(void* const* d_in, const int* in_sizes, int n_in,
                              void* d_out, int out_size, void* d_ws, size_t ws_size,
                              hipStream_t stream)
{
    const float* feat = (const float*)d_in[0];
    const float* k1   = (const float*)d_in[1];
    const float* b1   = (const float*)d_in[2];
    const float* k2   = (const float*)d_in[3];
    const float* b2   = (const float*)d_in[4];
    const float* k3   = (const float*)d_in[5];
    const float* b3   = (const float*)d_in[6];
    float* out = (float*)d_out;
    float* wts = (float*)d_ws;   // 4*NW floats, [par][o][pq][c]

    mlp_all_kernel<<<108, 256, 0, stream>>>(k1, b1, k2, b2, k3, b3, wts);
    upscale_kernel<<<512, 256, 0, stream>>>(feat, wts, out);
}